// Round 5
// baseline (53.094 us; speedup 1.0000x reference)
//
#include <hip/hip_runtime.h>
#include <math.h>

// Problem constants (match reference file)
#define B_ 64
#define K_ 16
#define N_ 65536
#define D_ 256
#define H_ 64

#define N4_ (N_ / 4)            // 16384 float4 columns per (b,k) row
#define CHUNKS_ 32              // blocks per batch element (R2-proven)
#define TPB_ 256
#define COLS_ (N4_ / CHUNKS_)   // 512 float4-cols per block
#define ITERS_ (COLS_ / TPB_)   // 2 iterations per thread (compiler fully unrolls)

#define MLP_BLOCKS_ 64          // first 64 blocks also run the tiny MLP (16 rows each)
#define ROWS_PER_BLK_ (B_ * K_ / MLP_BLOCKS_)   // 16

// ws layout (floats):
//   [0 .. 2048*32)      block-level partials: [block][ tot[0..16) | win[0..16) ]
//   [LQ_OFF_ .. +1024)  learned quality per (b,k)
#define PART_FLOATS_ (B_ * CHUNKS_ * 32)
#define LQ_OFF_ PART_FLOATS_

typedef float f32x4 __attribute__((ext_vector_type(4)));

__global__ __launch_bounds__(TPB_) void attn_stats_kernel(const float* __restrict__ attn,
                                                          const float* __restrict__ slots,
                                                          const float* __restrict__ W1,
                                                          const float* __restrict__ b1,
                                                          const float* __restrict__ W2,
                                                          const float* __restrict__ b2,
                                                          float* __restrict__ ws) {
    const int bid = blockIdx.x;
    const int b = bid / CHUNKS_;
    const int chunk = bid % CHUNKS_;
    const f32x4* base = reinterpret_cast<const f32x4*>(attn) +
                        (size_t)b * K_ * N4_ + (size_t)chunk * COLS_;

    float tot[K_], win[K_];
#pragma unroll
    for (int k = 0; k < K_; ++k) { tot[k] = 0.0f; win[k] = 0.0f; }

    for (int it = 0; it < ITERS_; ++it) {   // 2 trips, compiler fully unrolls (R2-proven)
        const int c = it * TPB_ + threadIdx.x;
        // k = 0 initializes the running argmax (winner's value IS the column max)
        // R4->R5 A/B: plain loads instead of __builtin_nontemporal_load
        f32x4 f = base[c];
        float m0 = f.x, m1 = f.y, m2 = f.z, m3 = f.w;
        int i0 = 0, i1 = 0, i2 = 0, i3 = 0;
        tot[0] += (f.x + f.y) + (f.z + f.w);
#pragma unroll
        for (int k = 1; k < K_; ++k) {
            f = base[(size_t)k * N4_ + c];
            tot[k] += (f.x + f.y) + (f.z + f.w);
            // strict > keeps the FIRST max, matching jnp.argmax tie-break
            if (f.x > m0) { m0 = f.x; i0 = k; }
            if (f.y > m1) { m1 = f.y; i1 = k; }
            if (f.z > m2) { m2 = f.z; i2 = k; }
            if (f.w > m3) { m3 = f.w; i3 = k; }
        }
        // scatter with static indexing (runtime-indexed VGPR arrays spill)
#pragma unroll
        for (int k = 0; k < K_; ++k) {
            win[k] += ((i0 == k) ? m0 : 0.0f) + ((i1 == k) ? m1 : 0.0f) +
                      ((i2 == k) ? m2 : 0.0f) + ((i3 == k) ? m3 : 0.0f);
        }
    }

    // intra-wave butterfly reduction (wave = 64 lanes on CDNA)
#pragma unroll
    for (int k = 0; k < K_; ++k) {
        float t = tot[k], w = win[k];
#pragma unroll
        for (int s = 1; s < 64; s <<= 1) {
            t += __shfl_xor(t, s, 64);
            w += __shfl_xor(w, s, 64);
        }
        tot[k] = t; win[k] = w;
    }

    // cross-wave reduction via LDS, then one coalesced 128 B partial write
    __shared__ float s_tot[4][K_];
    __shared__ float s_win[4][K_];
    const int lane = threadIdx.x & 63;
    const int wv = threadIdx.x >> 6;
    if (lane == 0) {
#pragma unroll
        for (int k = 0; k < K_; ++k) { s_tot[wv][k] = tot[k]; s_win[wv][k] = win[k]; }
    }
    __syncthreads();
    if (threadIdx.x < 2 * K_) {
        const int k = threadIdx.x & (K_ - 1);
        float v;
        if (threadIdx.x < K_) {
            v = (s_tot[0][k] + s_tot[1][k]) + (s_tot[2][k] + s_tot[3][k]);
        } else {
            v = (s_win[0][k] + s_win[1][k]) + (s_win[2][k] + s_win[3][k]);
        }
        ws[(size_t)bid * (2 * K_) + threadIdx.x] = v;
    }

    // ---- tiny MLP, only in the first 64 blocks (launched first -> overlaps the
    // ---- other blocks' streaming; W1 traffic = 64 x 64KB = 4 MB total).
    // Register-only, wave-independent: no __syncthreads needed.
    if (bid < MLP_BLOCKS_) {
        const int j = lane;                  // hidden unit 0..63
        const int g = wv;                    // wave 0..3 -> 4 rows each
        const int row0 = bid * ROWS_PER_BLK_ + g * 4;
        float a0 = 0.0f, a1 = 0.0f, a2 = 0.0f, a3 = 0.0f;
        const float* s0 = slots + (size_t)(row0 + 0) * D_;
        const float* s1 = slots + (size_t)(row0 + 1) * D_;
        const float* s2 = slots + (size_t)(row0 + 2) * D_;
        const float* s3 = slots + (size_t)(row0 + 3) * D_;
#pragma unroll 8
        for (int d = 0; d < D_; ++d) {
            const float w1v = W1[d * H_ + j];     // coalesced over j
            a0 = fmaf(s0[d], w1v, a0);            // wave-uniform -> scalar loads
            a1 = fmaf(s1[d], w1v, a1);
            a2 = fmaf(s2[d], w1v, a2);
            a3 = fmaf(s3[d], w1v, a3);
        }
        const float b1v = b1[j], w2v = W2[j];
        float v0 = fmaxf(a0 + b1v, 0.0f) * w2v;
        float v1 = fmaxf(a1 + b1v, 0.0f) * w2v;
        float v2 = fmaxf(a2 + b1v, 0.0f) * w2v;
        float v3 = fmaxf(a3 + b1v, 0.0f) * w2v;
#pragma unroll
        for (int s = 1; s < 64; s <<= 1) {
            v0 += __shfl_xor(v0, s, 64);
            v1 += __shfl_xor(v1, s, 64);
            v2 += __shfl_xor(v2, s, 64);
            v3 += __shfl_xor(v3, s, 64);
        }
        if (lane < 4) {
            const float val = (lane == 0) ? v0 : (lane == 1) ? v1 : (lane == 2) ? v2 : v3;
            ws[LQ_OFF_ + row0 + lane] = 1.0f / (1.0f + expf(-(val + b2[0])));
        }
    }
}

// 4 blocks x 256 threads: one thread per (b,k). Reduce 32 chunk partials + combine.
__global__ __launch_bounds__(256) void combine_kernel(const float* __restrict__ conf,
                                                      const float* __restrict__ ws,
                                                      float* __restrict__ out) {
    const int bk = blockIdx.x * 256 + threadIdx.x;   // 4 x 256 = 1024
    const int b = bk / K_;
    const int k = bk % K_;
    float tot = 0.0f, win = 0.0f;
#pragma unroll
    for (int ch = 0; ch < CHUNKS_; ++ch) {
        const float* p = ws + (size_t)(b * CHUNKS_ + ch) * (2 * K_);
        tot += p[k];
        win += p[K_ + k];
    }
    const float lq = ws[LQ_OFF_ + bk];
    const float aq = win / (tot + 1e-8f);
    const float q = 0.4f * aq + 0.4f * lq;
    out[bk] = q * 0.2f + conf[bk] * 0.8f;
}

extern "C" void kernel_launch(void* const* d_in, const int* in_sizes, int n_in,
                              void* d_out, int out_size, void* d_ws, size_t ws_size,
                              hipStream_t stream) {
    const float* slots = (const float*)d_in[0];   // [B,K,D]
    const float* attn  = (const float*)d_in[1];   // [B,K,N]
    const float* conf  = (const float*)d_in[2];   // [B,K]
    const float* W1    = (const float*)d_in[3];   // [D,H]
    const float* b1    = (const float*)d_in[4];   // [H]
    const float* W2    = (const float*)d_in[5];   // [H,1]
    const float* b2    = (const float*)d_in[6];   // [1]
    float* out = (float*)d_out;                   // [B,K]
    float* ws  = (float*)d_ws;                    // ~260 KiB used, fully overwritten

    attn_stats_kernel<<<B_ * CHUNKS_, TPB_, 0, stream>>>(attn, slots, W1, b1, W2, b2, ws);
    combine_kernel<<<(B_ * K_) / 256, 256, 0, stream>>>(conf, ws, out);
}

// Round 6
// 51.329 us; speedup vs baseline: 1.0344x; 1.0344x over previous
//
#include <hip/hip_runtime.h>
#include <math.h>

// Problem constants (match reference file)
#define B_ 64
#define K_ 16
#define N_ 65536
#define D_ 256
#define H_ 64

#define N4_ (N_ / 4)            // 16384 float4 columns per (b,k) row
#define CHUNKS_ 32              // blocks per batch element (R2/R4-proven)
#define TPB_ 256
#define COLS_ (N4_ / CHUNKS_)   // 512 float4-cols per block
#define ITERS_ (COLS_ / TPB_)   // 2 iterations per thread (compiler fully unrolls)

#define MLP_BLOCKS_ 64          // first 64 blocks also run the tiny MLP (16 rows each)
#define ROWS_PER_BLK_ (B_ * K_ / MLP_BLOCKS_)   // 16

// ws layout (floats), all regions fully overwritten every call:
//   [0 .. 32768)        tot partials, [b][k][chunk]  (chunk-contiguous for combine)
//   [32768 .. 65536)    win partials, [b][k][chunk]
//   [65536 .. 66560)    learned quality per (b,k)
#define WIN_OFF_ (B_ * K_ * CHUNKS_)
#define LQ_OFF_ (2 * B_ * K_ * CHUNKS_)

typedef float f32x4 __attribute__((ext_vector_type(4)));

__global__ __launch_bounds__(TPB_) void attn_stats_kernel(const float* __restrict__ attn,
                                                          const float* __restrict__ slots,
                                                          const float* __restrict__ W1,
                                                          const float* __restrict__ b1,
                                                          const float* __restrict__ W2,
                                                          const float* __restrict__ b2,
                                                          float* __restrict__ ws) {
    const int bid = blockIdx.x;
    const int b = bid / CHUNKS_;
    const int chunk = bid % CHUNKS_;
    const f32x4* base = reinterpret_cast<const f32x4*>(attn) +
                        (size_t)b * K_ * N4_ + (size_t)chunk * COLS_;

    float tot[K_], win[K_];
#pragma unroll
    for (int k = 0; k < K_; ++k) { tot[k] = 0.0f; win[k] = 0.0f; }

    for (int it = 0; it < ITERS_; ++it) {   // 2 trips, compiler fully unrolls
        const int c = it * TPB_ + threadIdx.x;
        // k = 0 initializes the running argmax (winner's value IS the column max)
        f32x4 f = __builtin_nontemporal_load(&base[c]);   // nt: +1.4us vs plain (R4/R5 A/B)
        float m0 = f.x, m1 = f.y, m2 = f.z, m3 = f.w;
        int i0 = 0, i1 = 0, i2 = 0, i3 = 0;
        tot[0] += (f.x + f.y) + (f.z + f.w);
#pragma unroll
        for (int k = 1; k < K_; ++k) {
            f = __builtin_nontemporal_load(&base[(size_t)k * N4_ + c]);
            tot[k] += (f.x + f.y) + (f.z + f.w);
            // strict > keeps the FIRST max, matching jnp.argmax tie-break
            if (f.x > m0) { m0 = f.x; i0 = k; }
            if (f.y > m1) { m1 = f.y; i1 = k; }
            if (f.z > m2) { m2 = f.z; i2 = k; }
            if (f.w > m3) { m3 = f.w; i3 = k; }
        }
        // scatter with static indexing (runtime-indexed VGPR arrays spill)
#pragma unroll
        for (int k = 0; k < K_; ++k) {
            win[k] += ((i0 == k) ? m0 : 0.0f) + ((i1 == k) ? m1 : 0.0f) +
                      ((i2 == k) ? m2 : 0.0f) + ((i3 == k) ? m3 : 0.0f);
        }
    }

    // intra-wave butterfly reduction (wave = 64 lanes on CDNA)
#pragma unroll
    for (int k = 0; k < K_; ++k) {
        float t = tot[k], w = win[k];
#pragma unroll
        for (int s = 1; s < 64; s <<= 1) {
            t += __shfl_xor(t, s, 64);
            w += __shfl_xor(w, s, 64);
        }
        tot[k] = t; win[k] = w;
    }

    // cross-wave reduction via LDS, then transposed partial write:
    // ws[{tot,win}][b][k][chunk] so the combine reads chunk-contiguous 128 B runs.
    __shared__ float s_tot[4][K_];
    __shared__ float s_win[4][K_];
    const int lane = threadIdx.x & 63;
    const int wv = threadIdx.x >> 6;
    if (lane == 0) {
#pragma unroll
        for (int k = 0; k < K_; ++k) { s_tot[wv][k] = tot[k]; s_win[wv][k] = win[k]; }
    }
    __syncthreads();
    if (threadIdx.x < 2 * K_) {
        const int k = threadIdx.x & (K_ - 1);
        float v;
        if (threadIdx.x < K_) {
            v = (s_tot[0][k] + s_tot[1][k]) + (s_tot[2][k] + s_tot[3][k]);
        } else {
            v = (s_win[0][k] + s_win[1][k]) + (s_win[2][k] + s_win[3][k]);
        }
        const size_t qoff = (threadIdx.x < K_) ? 0 : (size_t)WIN_OFF_;
        ws[qoff + ((size_t)b * K_ + k) * CHUNKS_ + chunk] = v;
    }

    // ---- tiny MLP, only in the first 64 blocks (launched first -> overlaps the
    // ---- other blocks' streaming; W1 traffic = 64 x 64KB = 4 MB total).
    // Register-only, wave-independent: no __syncthreads needed.
    if (bid < MLP_BLOCKS_) {
        const int j = lane;                  // hidden unit 0..63
        const int g = wv;                    // wave 0..3 -> 4 rows each
        const int row0 = bid * ROWS_PER_BLK_ + g * 4;
        float a0 = 0.0f, a1 = 0.0f, a2 = 0.0f, a3 = 0.0f;
        const float* s0 = slots + (size_t)(row0 + 0) * D_;
        const float* s1 = slots + (size_t)(row0 + 1) * D_;
        const float* s2 = slots + (size_t)(row0 + 2) * D_;
        const float* s3 = slots + (size_t)(row0 + 3) * D_;
#pragma unroll 8
        for (int d = 0; d < D_; ++d) {
            const float w1v = W1[d * H_ + j];     // coalesced over j
            a0 = fmaf(s0[d], w1v, a0);            // wave-uniform -> scalar loads
            a1 = fmaf(s1[d], w1v, a1);
            a2 = fmaf(s2[d], w1v, a2);
            a3 = fmaf(s3[d], w1v, a3);
        }
        const float b1v = b1[j], w2v = W2[j];
        float v0 = fmaxf(a0 + b1v, 0.0f) * w2v;
        float v1 = fmaxf(a1 + b1v, 0.0f) * w2v;
        float v2 = fmaxf(a2 + b1v, 0.0f) * w2v;
        float v3 = fmaxf(a3 + b1v, 0.0f) * w2v;
#pragma unroll
        for (int s = 1; s < 64; s <<= 1) {
            v0 += __shfl_xor(v0, s, 64);
            v1 += __shfl_xor(v1, s, 64);
            v2 += __shfl_xor(v2, s, 64);
            v3 += __shfl_xor(v3, s, 64);
        }
        if (lane < 4) {
            const float val = (lane == 0) ? v0 : (lane == 1) ? v1 : (lane == 2) ? v2 : v3;
            ws[LQ_OFF_ + row0 + lane] = 1.0f / (1.0f + expf(-(val + b2[0])));
        }
    }
}

// 128 blocks x 256 threads: one 32-lane group per (b,k). Coalesced 128 B reads
// of the chunk-contiguous partials + 5-step shuffle reduce.
__global__ __launch_bounds__(256) void combine_kernel(const float* __restrict__ conf,
                                                      const float* __restrict__ ws,
                                                      float* __restrict__ out) {
    const int bk = (blockIdx.x * 256 + threadIdx.x) >> 5;   // 0..1023
    const int ch = threadIdx.x & 31;
    float tot = ws[(size_t)bk * CHUNKS_ + ch];
    float win = ws[WIN_OFF_ + (size_t)bk * CHUNKS_ + ch];
#pragma unroll
    for (int s = 1; s < 32; s <<= 1) {   // xor strides < 32 stay within the 32-lane group
        tot += __shfl_xor(tot, s, 64);
        win += __shfl_xor(win, s, 64);
    }
    if (ch == 0) {
        const float lq = ws[LQ_OFF_ + bk];
        const float aq = win / (tot + 1e-8f);
        const float q = 0.4f * aq + 0.4f * lq;
        out[bk] = q * 0.2f + conf[bk] * 0.8f;
    }
}

extern "C" void kernel_launch(void* const* d_in, const int* in_sizes, int n_in,
                              void* d_out, int out_size, void* d_ws, size_t ws_size,
                              hipStream_t stream) {
    const float* slots = (const float*)d_in[0];   // [B,K,D]
    const float* attn  = (const float*)d_in[1];   // [B,K,N]
    const float* conf  = (const float*)d_in[2];   // [B,K]
    const float* W1    = (const float*)d_in[3];   // [D,H]
    const float* b1    = (const float*)d_in[4];   // [H]
    const float* W2    = (const float*)d_in[5];   // [H,1]
    const float* b2    = (const float*)d_in[6];   // [1]
    float* out = (float*)d_out;                   // [B,K]
    float* ws  = (float*)d_ws;                    // ~260 KiB used, fully overwritten

    attn_stats_kernel<<<B_ * CHUNKS_, TPB_, 0, stream>>>(attn, slots, W1, b1, W2, b2, ws);
    combine_kernel<<<(B_ * K_ * 32) / 256, 256, 0, stream>>>(conf, ws, out);
}